// Round 4
// baseline (100.496 us; speedup 1.0000x reference)
//
#include <hip/hip_runtime.h>

#define BATCH 8
#define CC 32
#define FF 4
#define HH 128
#define WW 128
#define STRIDE 129          // W+1; 129 % 32 == 1 -> conflict-free scans
#define RP 1024.0f          // REPARAM_H == REPARAM_W
#define NTHREADS 512
#define NWAVES 8
#define CH 16               // consecutive h-rows per wave per filter
#define DEW 244             // guarded D row: [0,48) left guard, [48,176] data, [176,240) right guard
#define DEBASE 48

__global__ __launch_bounds__(NTHREADS) void boxconv_kernel(
    const float* __restrict__ in,
    const float* __restrict__ xmin_p,
    const float* __restrict__ xmax_p,
    const float* __restrict__ ymin_p,
    const float* __restrict__ ymax_p,
    float* __restrict__ out)
{
    __shared__ float ii[(HH + 1) * STRIDE];        // 66564 B
    __shared__ float de[NWAVES * DEW];             // 7808 B
    __shared__ float partial[4 * 128];             // 2048 B   -> total 76420 B: 2 blocks/CU

    const int bid = blockIdx.x;
    const int plane = bid & 255;                   // plane-major: both f-pair blocks same XCD
    const int fpair = bid >> 8;
    const int c = plane & (CC - 1);
    const int tid = threadIdx.x;
    const int wave = tid >> 6;
    const int lane = tid & 63;
    const float* inp = in + (size_t)plane * (HH * WW);

    // ---- stage input plane into ii[(x+1)*STRIDE + (y+1)]
    for (int i4 = tid; i4 < (HH * WW) / 4; i4 += NTHREADS) {
        const float4 v = ((const float4*)inp)[i4];
        const int idx = i4 << 2;
        const int x = idx >> 7;
        const int y = idx & (WW - 1);
        float* dst = &ii[(x + 1) * STRIDE + (y + 1)];
        dst[0] = v.x; dst[1] = v.y; dst[2] = v.z; dst[3] = v.w;
    }
    if (tid <= HH) {                               // zero border row 0 / col 0
        ii[tid] = 0.0f;
        ii[tid * STRIDE] = 0.0f;
    }
    if (lane < DEBASE) de[wave * DEW + lane] = 0.0f;   // left guard, stays 0
    __syncthreads();

    // ---- row cumsum, 4-way segmented (512 threads)
    {
        const int row = tid & 127, seg = tid >> 7;
        float* p = &ii[(row + 1) * STRIDE + 1 + seg * 32];
        float v[32];
        float s = 0.0f;
        #pragma unroll
        for (int j = 0; j < 32; ++j) { s += p[j]; v[j] = s; }
        partial[seg * 128 + row] = s;
        __syncthreads();
        float off = 0.0f;
        for (int k = 0; k < seg; ++k) off += partial[k * 128 + row];
        #pragma unroll
        for (int j = 0; j < 32; ++j) p[j] = v[j] + off;
    }
    __syncthreads();

    // ---- col cumsum, 4-way segmented
    {
        const int col = tid & 127, seg = tid >> 7;
        float* p = &ii[(seg * 32 + 1) * STRIDE + col + 1];
        float v[32];
        float s = 0.0f;
        #pragma unroll
        for (int j = 0; j < 32; ++j) { s += p[j * STRIDE]; v[j] = s; }
        partial[seg * 128 + col] = s;
        __syncthreads();
        float off = 0.0f;
        for (int k = 0; k < seg; ++k) off += partial[k * 128 + col];
        #pragma unroll
        for (int j = 0; j < 32; ++j) p[j * STRIDE] = v[j] + off;
    }
    __syncthreads();                               // last barrier — compute is barrier-free

    // ---- compute: register-carried D-build over CH consecutive rows, guarded stencil
    float* De = &de[wave * DEW];
    const int h0 = wave * CH;

    for (int ff = 0; ff < 2; ++ff) {
        const int f = fpair * 2 + ff;
        const int pidx = c * FF + f;
        const float xmn = xmin_p[pidx] * RP;
        const float xmx = xmax_p[pidx] * RP;
        const float ymn = ymin_p[pidx] * RP;
        const float ymx = ymax_p[pidx] * RP;
        const float inv_area = 1.0f / ((xmx - xmn + 1.0f) * (ymx - ymn + 1.0f));
        const float ktf = floorf(xmn);          const int kt = (int)ktf;  const float ft = xmn - ktf;
        const float kbf = floorf(xmx + 1.0f);   const int kb = (int)kbf;  const float fb = xmx + 1.0f - kbf;
        const float klf = floorf(ymn);          const int kl = (int)klf;  const float fl = ymn - klf;
        const float krf = floorf(ymx + 1.0f);   const int kr = (int)krf;  const float fr = ymx + 1.0f - krf;
        const float gt = 1.0f - ft, gb = 1.0f - fb, gl = 1.0f - fl, gr = 1.0f - fr;
        const float* DlBase = De + DEBASE + kl;    // kl in [-43,-2]
        const float* DrBase = De + DEBASE + kr;    // kr in [ 3, 44]; max read idx 48+44+128 = 220 < 240
        float* outf = out + ((size_t)plane * FF + f) * (HH * WW);

        // virtual extension: row(x<0) == 0 (ii row0 is zero), row(x>128) == row(128)
        // so clamp(x,0,128) + constant weights reproduces the reference clipping exactly.
        int xt = h0 + kt;                          // row indices for j=0
        int xb = h0 + kb;
        float tp0, tp1, tp2, bp0, bp1, bp2;
        {
            const float* p = &ii[min(max(xt, 0), 128) * STRIDE];
            tp0 = p[lane]; tp1 = p[lane + 64]; tp2 = p[128];
            const float* q = &ii[min(max(xb, 0), 128) * STRIDE];
            bp0 = q[lane]; bp1 = q[lane + 64]; bp2 = q[128];
        }

        for (int j = 0; j < CH; ++j) {
            const float* p = &ii[min(max(xt + j + 1, 0), 128) * STRIDE];
            const float tc0 = p[lane], tc1 = p[lane + 64], tc2 = p[128];
            const float* q = &ii[min(max(xb + j + 1, 0), 128) * STRIDE];
            const float bc0 = q[lane], bc1 = q[lane + 64], bc2 = q[128];

            const float d0   = (gb * bp0 + fb * bc0) - (gt * tp0 + ft * tc0);
            const float d1   = (gb * bp1 + fb * bc1) - (gt * tp1 + ft * tc1);
            const float d128 = (gb * bp2 + fb * bc2) - (gt * tp2 + ft * tc2);

            De[DEBASE + lane]        = d0;
            De[DEBASE + 64 + lane]   = d1;
            De[DEBASE + 128 + lane]  = d128;       // idx128 = D[128]; [129,192) right guard == D[128]

            // pixel phase: fixed-shift stencil, lane covers w = lane, lane+64
            const float l0a = DlBase[lane],      l0b = DlBase[lane + 1];
            const float l1a = DlBase[lane + 64], l1b = DlBase[lane + 65];
            const float r0a = DrBase[lane],      r0b = DrBase[lane + 1];
            const float r1a = DrBase[lane + 64], r1b = DrBase[lane + 65];
            const float o0 = (gr * r0a + fr * r0b - gl * l0a - fl * l0b) * inv_area;
            const float o1 = (gr * r1a + fr * r1b - gl * l1a - fl * l1b) * inv_area;
            float* outr = outf + (h0 + j) * WW + lane;
            outr[0]  = o0;
            outr[64] = o1;

            tp0 = tc0; tp1 = tc1; tp2 = tc2;
            bp0 = bc0; bp1 = bc1; bp2 = bc2;
        }
    }
}

extern "C" void kernel_launch(void* const* d_in, const int* in_sizes, int n_in,
                              void* d_out, int out_size, void* d_ws, size_t ws_size,
                              hipStream_t stream) {
    const float* inp    = (const float*)d_in[0];
    const float* x_min  = (const float*)d_in[1];
    const float* x_max  = (const float*)d_in[2];
    const float* y_min  = (const float*)d_in[3];
    const float* y_max  = (const float*)d_in[4];
    float* out = (float*)d_out;

    dim3 grid(2 * BATCH * CC);   // (plane, f-pair): 512 blocks, 2 per CU
    dim3 block(NTHREADS);        // 8 waves
    boxconv_kernel<<<grid, block, 0, stream>>>(inp, x_min, x_max, y_min, y_max, out);
}

// Round 5
// 96.690 us; speedup vs baseline: 1.0394x; 1.0394x over previous
//
#include <hip/hip_runtime.h>

#define BATCH 8
#define CC 32
#define FF 4
#define HH 128
#define WW 128
#define STRIDE 130          // even -> float2 (b64) aligned row reads; col scan conflict-free
#define RP 1024.0f          // REPARAM_H == REPARAM_W
#define NTHREADS 1024
#define NWAVES 16
#define CH 8                // consecutive h-rows per wave per filter (128/16)
#define DEW 240             // guarded D row: [0,48) zero guard, [48,176] data, [176,240) right guard
#define DEBASE 48

__global__ __launch_bounds__(NTHREADS) void boxconv_kernel(
    const float* __restrict__ in,
    const float* __restrict__ xmin_p,
    const float* __restrict__ xmax_p,
    const float* __restrict__ ymin_p,
    const float* __restrict__ ymax_p,
    float* __restrict__ out)
{
    __shared__ float ii[(HH + 1) * STRIDE];        // 129*130*4 = 67080 B
    __shared__ float de[NWAVES * DEW];             // 15360 B
    __shared__ float partial[8 * 128];             // 4096 B -> total ~86.5 KB, 1 block/CU

    const int plane = blockIdx.x;                  // b*CC + c
    const int c = plane & (CC - 1);
    const int tid = threadIdx.x;
    const int wave = tid >> 6;
    const int lane = tid & 63;
    const float* inp = in + (size_t)plane * (HH * WW);

    // ---- stage input plane into ii[(x+1)*STRIDE + (y+1)]
    for (int i4 = tid; i4 < (HH * WW) / 4; i4 += NTHREADS) {
        const float4 v = ((const float4*)inp)[i4];
        const int idx = i4 << 2;
        const int x = idx >> 7;
        const int y = idx & (WW - 1);
        float* dst = &ii[(x + 1) * STRIDE + (y + 1)];
        dst[0] = v.x; dst[1] = v.y; dst[2] = v.z; dst[3] = v.w;
    }
    if (tid <= HH) {                               // zero border row 0 / col 0
        ii[tid] = 0.0f;
        ii[tid * STRIDE] = 0.0f;
    }
    if (lane < DEBASE) de[wave * DEW + lane] = 0.0f;   // left guard, stays 0 forever
    __syncthreads();

    // ---- row cumsum, 8-way segmented
    {
        const int row = tid & 127, seg = tid >> 7;
        float* p = &ii[(row + 1) * STRIDE + 1 + seg * 16];
        float v[16];
        float s = 0.0f;
        #pragma unroll
        for (int j = 0; j < 16; ++j) { s += p[j]; v[j] = s; }
        partial[seg * 128 + row] = s;
        __syncthreads();
        float off = 0.0f;
        for (int k = 0; k < seg; ++k) off += partial[k * 128 + row];
        #pragma unroll
        for (int j = 0; j < 16; ++j) p[j] = v[j] + off;
    }
    __syncthreads();

    // ---- col cumsum, 8-way segmented
    {
        const int col = tid & 127, seg = tid >> 7;
        float* p = &ii[(seg * 16 + 1) * STRIDE + col + 1];
        float v[16];
        float s = 0.0f;
        #pragma unroll
        for (int j = 0; j < 16; ++j) { s += p[j * STRIDE]; v[j] = s; }
        partial[seg * 128 + col] = s;
        __syncthreads();
        float off = 0.0f;
        for (int k = 0; k < seg; ++k) off += partial[k * 128 + col];
        #pragma unroll
        for (int j = 0; j < 16; ++j) p[j * STRIDE] = v[j] + off;
    }
    __syncthreads();                               // last barrier — compute is barrier-free

    // ---- compute: 2 px/lane, b64 LDS ops, register-carried D-build
    float* De = &de[wave * DEW];
    const int h0 = wave * CH;

    for (int f = 0; f < FF; ++f) {
        const int pidx = c * FF + f;
        const float xmn = xmin_p[pidx] * RP;
        const float xmx = xmax_p[pidx] * RP;
        const float ymn = ymin_p[pidx] * RP;
        const float ymx = ymax_p[pidx] * RP;
        const float inv_area = 1.0f / ((xmx - xmn + 1.0f) * (ymx - ymn + 1.0f));
        const float ktf = floorf(xmn);          const int kt = (int)ktf;  const float ft = xmn - ktf;
        const float kbf = floorf(xmx + 1.0f);   const int kb = (int)kbf;  const float fb = xmx + 1.0f - kbf;
        const float klf = floorf(ymn);          const int kl = (int)klf;  const float fl = ymn - klf;
        const float krf = floorf(ymx + 1.0f);   const int kr = (int)krf;  const float fr = ymx + 1.0f - krf;
        const float gt = 1.0f - ft, gb = 1.0f - fb, gl = 1.0f - fl, gr = 1.0f - fr;
        const int al = kl & ~1, dl = kl - al;      // even base + uniform select in {0,1}
        const int ar = kr & ~1, dr = kr - ar;
        const float* Lp = &De[DEBASE + al + 2 * lane];   // min word 48-44 = 4 >= 0
        const float* Rp = &De[DEBASE + ar + 2 * lane];   // max word 48+44+126+3 = 221 < 240
        float* outf = out + ((size_t)plane * FF + f) * (HH * WW);

        // virtual extension: row(x<0)==0 (ii row0 zero), row(x>128)==row(128) (gb+fb=1)
        const int xt = h0 + kt;
        const int xb = h0 + kb;
        const float* p0 = &ii[min(max(xt, 0), 128) * STRIDE];
        const float* q0 = &ii[min(max(xb, 0), 128) * STRIDE];
        float2 tp = *(const float2*)&p0[2 * lane];
        float  tp2 = p0[128];
        float2 bp = *(const float2*)&q0[2 * lane];
        float  bp2 = q0[128];

        #pragma unroll
        for (int j = 0; j < CH; ++j) {
            const float* p = &ii[min(max(xt + j + 1, 0), 128) * STRIDE];
            const float* q = &ii[min(max(xb + j + 1, 0), 128) * STRIDE];
            const float2 tc = *(const float2*)&p[2 * lane];
            const float  tc2 = p[128];
            const float2 bc = *(const float2*)&q[2 * lane];
            const float  bc2 = q[128];

            const float d0   = (gb * bp.x + fb * bc.x) - (gt * tp.x + ft * tc.x);
            const float d1   = (gb * bp.y + fb * bc.y) - (gt * tp.y + ft * tc.y);
            const float d128 = (gb * bp2  + fb * bc2 ) - (gt * tp2  + ft * tc2 );

            *(float2*)&De[DEBASE + 2 * lane] = make_float2(d0, d1);
            De[DEBASE + 128 + lane] = d128;        // D[128] + right guard (y>=128 -> D[128])

            // stencil: 4-word windows, uniform dl/dr pick the odd/even alignment
            const float2 vL0 = *(const float2*)(Lp);
            const float2 vL1 = *(const float2*)(Lp + 2);
            const float2 vR0 = *(const float2*)(Rp);
            const float2 vR1 = *(const float2*)(Rp + 2);
            const float La = dl ? vL0.y : vL0.x;
            const float Lb = dl ? vL1.x : vL0.y;
            const float Lc = dl ? vL1.y : vL1.x;
            const float Ra = dr ? vR0.y : vR0.x;
            const float Rb = dr ? vR1.x : vR0.y;
            const float Rc = dr ? vR1.y : vR1.x;

            const float o0 = (gr * Ra + fr * Rb - gl * La - fl * Lb) * inv_area;
            const float o1 = (gr * Rb + fr * Rc - gl * Lb - fl * Lc) * inv_area;
            *(float2*)&outf[(h0 + j) * WW + 2 * lane] = make_float2(o0, o1);

            tp = tc; tp2 = tc2; bp = bc; bp2 = bc2;
        }
    }
}

extern "C" void kernel_launch(void* const* d_in, const int* in_sizes, int n_in,
                              void* d_out, int out_size, void* d_ws, size_t ws_size,
                              hipStream_t stream) {
    const float* inp    = (const float*)d_in[0];
    const float* x_min  = (const float*)d_in[1];
    const float* x_max  = (const float*)d_in[2];
    const float* y_min  = (const float*)d_in[3];
    const float* y_max  = (const float*)d_in[4];
    float* out = (float*)d_out;

    dim3 grid(BATCH * CC);      // one block per (b,c) plane, 1 per CU
    dim3 block(NTHREADS);       // 16 waves
    boxconv_kernel<<<grid, block, 0, stream>>>(inp, x_min, x_max, y_min, y_max, out);
}